// Round 5
// baseline (140.693 us; speedup 1.0000x reference)
//
#include <hip/hip_runtime.h>

#define CDIM   45
#define LMAXX  8
#define VOXPB  64
#define VDIM   64

// ---------------- compile-time SH constant tables ----------------
constexpr double PI_D = 3.14159265358979323846;

constexpr double dfactd(int n){ double o=1.0; for(int k=n;k>1;k-=2) o*=k; return o; }
constexpr double factd (int n){ double o=1.0; for(int k=2;k<=n;++k) o*=k; return o; }
constexpr double csqrtd(double x){
  if(x<=0.0) return 0.0;
  double g = x>1.0 ? x : 1.0;
  for(int i=0;i<200;++i) g = 0.5*(g + x/g);
  return g;
}

struct SHTab {
  float c1[LMAXX+1][LMAXX+1];  // (2l-1)/(l-m)
  float c2[LMAXX+1][LMAXX+1];  // (l+m-1)/(l-m)
  float qmm[LMAXX+1];          // (-1)^m (2m-1)!!
  float qnx[LMAXX+1];          // (2m+1)*qmm
  float CP [LMAXX+1][LMAXX+1]; // combined: m==0 ? K : sgn*sqrt2*K
};

constexpr SHTab makeTab(){
  SHTab t{};
  for(int m=0;m<=LMAXX;++m){
    double q = ((m&1)?-1.0:1.0)*dfactd(2*m-1);
    t.qmm[m]=(float)q;
    t.qnx[m]=(float)((2.0*m+1.0)*q);
    for(int l=m+2;l<=LMAXX;++l){
      t.c1[m][l]=(float)((2.0*l-1.0)/(double)(l-m));
      t.c2[m][l]=(float)((double)(l+m-1)/(double)(l-m));
    }
    for(int l=m;l<=LMAXX;++l){
      double K = csqrtd((2.0*l+1.0)/(4.0*PI_D)*factd(l-m)/factd(l+m));
      double v = (m==0)? K : (((m&1)?-1.0:1.0)*csqrtd(2.0)*K);
      t.CP[m][l]=(float)v;
    }
  }
  return t;
}
constexpr SHTab SHT = makeTab();

// block offsets for even l: l=0,2,4,6,8 -> 0,1,6,15,28 ; idx(l,m)=offL(l)+l+m
__device__ __host__ constexpr int offL(int l){
  return l==0?0 : (l==2?1 : (l==4?6 : (l==6?15 : 28)));
}

__device__ __forceinline__ void inv3x3(const float* __restrict__ ap,
                                       float& det,
                                       float& i00,float& i01,float& i02,
                                       float& i10,float& i11,float& i12,
                                       float& i20,float& i21,float& i22)
{
  float a0=ap[0],a1=ap[1],a2=ap[2],a3=ap[3],a4=ap[4],a5=ap[5],a6=ap[6],a7=ap[7],a8=ap[8];
  det = a0*(a4*a8-a5*a7) - a1*(a3*a8-a5*a6) + a2*(a3*a7-a4*a6);
  const float rdet = 1.0f/det;
  i00 =  (a4*a8-a5*a7)*rdet;
  i01 = -(a1*a8-a2*a7)*rdet;
  i02 =  (a1*a5-a2*a4)*rdet;
  i10 = -(a3*a8-a5*a6)*rdet;
  i11 =  (a0*a8-a2*a6)*rdet;
  i12 = -(a0*a5-a2*a3)*rdet;
  i20 =  (a3*a7-a4*a6)*rdet;
  i21 = -(a0*a7-a1*a6)*rdet;
  i22 =  (a0*a4-a1*a3)*rdet;
}

// SH evaluation + accumulate: PLAIN unrolled loops (no template lambdas) so
// the compiler fully inlines/unrolls and SROA keeps acc[] in VGPRs.
__device__ __forceinline__ void sh_accum(float px, float py, float pz,
                                         float wmod, float* __restrict__ acc)
{
  float Ap = 1.0f, Bp = 0.0f;
  #pragma unroll
  for (int m = 0; m <= LMAXX; ++m){
    float Ac, Bc;
    if (m == 0){ Ac = 1.0f; Bc = 0.0f; }
    else { Ac = fmaf(px, Ap, -(py*Bp)); Bc = fmaf(px, Bp, py*Ap); }
    const float fa = wmod * Ac;
    const float fb = wmod * Bc;
    float qp2 = SHT.qmm[m];          // Q[m][m]
    float qp1 = SHT.qnx[m] * pz;     // Q[m+1][m]
    if ((m & 1) == 0){               // l = m is even: emit from qp2
      const float t = qp2 * SHT.CP[m][m];
      if (m == 0){
        acc[0] = fmaf(t, wmod, acc[0]);
      } else {
        acc[offL(m)+2*m] = fmaf(t, fa, acc[offL(m)+2*m]);
        acc[offL(m)     ] = fmaf(t, fb, acc[offL(m)     ]);
      }
    } else {                         // l = m+1 is even: emit from qp1
      const int L = m + 1;
      const float t = qp1 * SHT.CP[m][L];
      acc[offL(L)+L+m] = fmaf(t, fa, acc[offL(L)+L+m]);
      acc[offL(L)+L-m] = fmaf(t, fb, acc[offL(L)+L-m]);
    }
    #pragma unroll
    for (int l = m + 2; l <= LMAXX; ++l){
      const float q = fmaf(SHT.c1[m][l]*pz, qp1, -(SHT.c2[m][l]*qp2));
      qp2 = qp1; qp1 = q;
      if ((l & 1) == 0){
        const float t = q * SHT.CP[m][l];
        if (m == 0){
          acc[offL(l)+l] = fmaf(t, wmod, acc[offL(l)+l]);
        } else {
          acc[offL(l)+l+m] = fmaf(t, fa, acc[offL(l)+l+m]);
          acc[offL(l)+l-m] = fmaf(t, fb, acc[offL(l)+l-m]);
        }
      }
    }
    Ap = Ac; Bp = Bc;
  }
}

// ================= K1: modulated PSF weights =================
// 256 thr = 4 waves; lane = voxel, each wave 16 vectors.
// wws[v*Nvox + n] = |A^{-1}v| * det(A) * dot(Mp[v,:], img[n,:])
__global__ __launch_bounds__(256)
__attribute__((amdgpu_waves_per_eu(2,4)))
void k1_weights(const float* __restrict__ image,
                const float* __restrict__ affine,
                const float* __restrict__ psf,
                const float* __restrict__ Mp,
                float* __restrict__ wws,
                int Nvox)
{
  const int lane = threadIdx.x & 63;
  const int wvi  = __builtin_amdgcn_readfirstlane(threadIdx.x >> 6); // 0..3
  const int voxBase = blockIdx.x * VOXPB;
  int vox = voxBase + lane;
  const bool valid = vox < Nvox;
  if (!valid) vox = Nvox - 1;

  float img[CDIM];
  {
    const float* ip = image + (size_t)vox * CDIM;
    #pragma unroll
    for(int c=0;c<CDIM;++c) img[c] = ip[c];
  }
  float det,i00,i01,i02,i10,i11,i12,i20,i21,i22;
  inv3x3(affine + (size_t)vox*9, det, i00,i01,i02,i10,i11,i12,i20,i21,i22);

  const int vbase = wvi * 16;
  #pragma unroll 1
  for(int k=0;k<16;++k){
    const int v = vbase + k;
    const float sxv = psf[3*v+0];
    const float syv = psf[3*v+1];
    const float szv = psf[3*v+2];
    const float hx = fmaf(i00,sxv, fmaf(i01,syv, i02*szv));
    const float hy = fmaf(i10,sxv, fmaf(i11,syv, i12*szv));
    const float hz = fmaf(i20,sxv, fmaf(i21,syv, i22*szv));
    const float r2  = fmaf(hx,hx, fmaf(hy,hy, hz*hz));
    const float rin = rsqrtf(r2 + 1e-12f);

    const float* Mrow = Mp + v*CDIM;                 // wave-uniform -> s_loads
    float w0=0.f,w1=0.f,w2=0.f,w3=0.f;
    #pragma unroll
    for(int c=0;c<44;c+=4){
      w0 = fmaf(Mrow[c+0], img[c+0], w0);
      w1 = fmaf(Mrow[c+1], img[c+1], w1);
      w2 = fmaf(Mrow[c+2], img[c+2], w2);
      w3 = fmaf(Mrow[c+3], img[c+3], w3);
    }
    w0 = fmaf(Mrow[44], img[44], w0);
    const float wval = (w0+w1)+(w2+w3);
    if (valid)
      wws[(size_t)v*Nvox + vox] = r2*rin*det*wval;   // sqrt(r2)=r2*rsqrt(r2)
  }
}

// ================= K2: SH evaluation + accumulate =================
// 512 thr = 8 waves; lane = voxel, each wave 8 vectors. acc[45] in VGPRs.
__global__ __launch_bounds__(512)
__attribute__((amdgpu_waves_per_eu(2,4)))
void k2_sh(const float* __restrict__ affine,
           const float* __restrict__ psf,
           const float* __restrict__ wws,
           float* __restrict__ out,
           int Nvox)
{
  __shared__ float red[VOXPB*CDIM];   // stride 45: odd -> 2-way bank alias (free)

  const int tid  = threadIdx.x;
  const int lane = tid & 63;
  const int wvi  = __builtin_amdgcn_readfirstlane(tid >> 6); // 0..7
  const int voxBase = blockIdx.x * VOXPB;
  int vox = voxBase + lane;
  if (vox >= Nvox) vox = Nvox - 1;

  #pragma unroll 1
  for (int i = tid; i < VOXPB*CDIM; i += 512) red[i] = 0.0f;
  __syncthreads();

  const int vbase = wvi * 8;

  // prefetch this wave's 8 wmod values (coalesced, independent)
  float wpre[8];
  #pragma unroll
  for(int k=0;k<8;++k) wpre[k] = wws[(size_t)(vbase+k)*Nvox + vox];

  float det,i00,i01,i02,i10,i11,i12,i20,i21,i22;
  inv3x3(affine + (size_t)vox*9, det, i00,i01,i02,i10,i11,i12,i20,i21,i22);

  float acc[CDIM];
  #pragma unroll
  for(int c=0;c<CDIM;++c) acc[c]=0.0f;

  #pragma unroll 1
  for(int k=0;k<8;++k){
    const int v = vbase + k;
    const float sxv = psf[3*v+0];
    const float syv = psf[3*v+1];
    const float szv = psf[3*v+2];
    const float hx = fmaf(i00,sxv, fmaf(i01,syv, i02*szv));
    const float hy = fmaf(i10,sxv, fmaf(i11,syv, i12*szv));
    const float hz = fmaf(i20,sxv, fmaf(i21,syv, i22*szv));
    const float r2  = fmaf(hx,hx, fmaf(hy,hy, hz*hz));
    const float rin = rsqrtf(r2 + 1e-12f);
    // xyz -> yzx permute, then normalize
    const float px = hy*rin;
    const float py = hz*rin;
    const float pz = hx*rin;

    sh_accum(px, py, pz, wpre[k], acc);
  }

  // cross-wave reduction: LDS float atomics (ds_add), linear stride-45 rows
  #pragma unroll
  for(int c=0;c<CDIM;++c) atomicAdd(&red[lane*CDIM + c], acc[c]);
  __syncthreads();

  // linear, coalesced store
  #pragma unroll 1
  for(int i = tid; i < VOXPB*CDIM; i += 512){
    const int vx = i / CDIM;
    if (voxBase + vx < Nvox)
      out[(size_t)voxBase*CDIM + i] = red[i];
  }
}

// ---------------- launch ----------------
extern "C" void kernel_launch(void* const* d_in, const int* in_sizes, int n_in,
                              void* d_out, int out_size, void* d_ws, size_t ws_size,
                              hipStream_t stream)
{
  const float* image  = (const float*)d_in[0];
  const float* affine = (const float*)d_in[1];
  const float* psf    = (const float*)d_in[2];
  const float* Mp     = (const float*)d_in[3];
  float* out = (float*)d_out;
  float* wws = (float*)d_ws;                 // 64 * Nvox floats = 8 MB << ws_size

  const int Nvox = in_sizes[0] / CDIM;
  const int blocks = (Nvox + VOXPB - 1) / VOXPB;

  hipLaunchKernelGGL(k1_weights, dim3(blocks), dim3(256), 0, stream,
                     image, affine, psf, Mp, wws, Nvox);
  hipLaunchKernelGGL(k2_sh, dim3(blocks), dim3(512), 0, stream,
                     affine, psf, wws, out, Nvox);
}

// Round 6
// 79.975 us; speedup vs baseline: 1.7592x; 1.7592x over previous
//
#include <hip/hip_runtime.h>
#include <type_traits>
#include <utility>

#define CDIM   45
#define LMAXX  8
#define WAVES_PB 4
#define VOXPB  64
#define VDIM   64
#define VPT    (VDIM / WAVES_PB)

// ---------------- compile-time SH constant tables ----------------
constexpr double PI_D = 3.14159265358979323846;

constexpr double dfactd(int n){ double o=1.0; for(int k=n;k>1;k-=2) o*=k; return o; }
constexpr double factd (int n){ double o=1.0; for(int k=2;k<=n;++k) o*=k; return o; }
constexpr double csqrtd(double x){
  if(x<=0.0) return 0.0;
  double g = x>1.0 ? x : 1.0;
  for(int i=0;i<200;++i) g = 0.5*(g + x/g);
  return g;
}

struct SHTab {
  float c1[LMAXX+1][LMAXX+1];  // (2l-1)/(l-m)
  float c2[LMAXX+1][LMAXX+1];  // (l+m-1)/(l-m)
  float qmm[LMAXX+1];          // (-1)^m (2m-1)!!
  float qnx[LMAXX+1];          // (2m+1)*qmm
  float CP [LMAXX+1][LMAXX+1]; // combined: m==0 ? K : sgn*sqrt2*K
};

constexpr SHTab makeTab(){
  SHTab t{};
  for(int m=0;m<=LMAXX;++m){
    double q = ((m&1)?-1.0:1.0)*dfactd(2*m-1);
    t.qmm[m]=(float)q;
    t.qnx[m]=(float)((2.0*m+1.0)*q);
    for(int l=m+2;l<=LMAXX;++l){
      t.c1[m][l]=(float)((2.0*l-1.0)/(double)(l-m));
      t.c2[m][l]=(float)((double)(l+m-1)/(double)(l-m));
    }
    for(int l=m;l<=LMAXX;++l){
      double K = csqrtd((2.0*l+1.0)/(4.0*PI_D)*factd(l-m)/factd(l+m));
      double v = (m==0)? K : (((m&1)?-1.0:1.0)*csqrtd(2.0)*K);
      t.CP[m][l]=(float)v;
    }
  }
  return t;
}
constexpr SHTab SHT = makeTab();

// block offsets for even l: l=0,2,4,6,8 -> 0,1,6,15,28 ; idx(l,m)=offL(l)+l+m
constexpr int offL(int l){ return l==0?0 : (l==2?1 : (l==4?6 : (l==6?15 : 28))); }

// compile-time unroller (indices are constants -> acc[] stays in registers)
template<int N, typename F>
__device__ __forceinline__ void cunroll(F&& f){
  if constexpr (N > 0){
    cunroll<N-1>(f);
    f(std::integral_constant<int, N-1>{});
  }
}

// ---------------- kernel ----------------
__global__ __launch_bounds__(256, 2)
void fodf_reorient_kernel(const float* __restrict__ image,
                          const float* __restrict__ affine,
                          const float* __restrict__ psf,
                          const float* __restrict__ Mp,
                          float* __restrict__ out,
                          int Nvox)
{
  __shared__ float red[WAVES_PB][VOXPB][CDIM+3];   // pad 45->48 floats

  const int tid  = threadIdx.x;
  const int lane = tid & 63;
  const int wvi  = __builtin_amdgcn_readfirstlane(tid >> 6); // wave id 0..3 (uniform)
  const int voxBase = blockIdx.x * VOXPB;
  const int vox  = voxBase + lane;
  const bool valid = vox < Nvox;

  // ---- per-voxel loads (one lane = one voxel) ----
  float img[CDIM];
  if (valid){
    const float* ip = image + (long long)vox * CDIM;
    #pragma unroll
    for(int c=0;c<CDIM;++c) img[c] = ip[c];
  } else {
    #pragma unroll
    for(int c=0;c<CDIM;++c) img[c] = 0.0f;
  }

  float a[9];
  if (valid){
    const float* ap = affine + (long long)vox * 9;
    #pragma unroll
    for(int i=0;i<9;++i) a[i] = ap[i];
  } else {
    #pragma unroll
    for(int i=0;i<9;++i) a[i] = (i%4==0) ? 1.0f : 0.0f;   // identity
  }

  // ---- 3x3 inverse via adjugate ----
  const float det = a[0]*(a[4]*a[8]-a[5]*a[7])
                  - a[1]*(a[3]*a[8]-a[5]*a[6])
                  + a[2]*(a[3]*a[7]-a[4]*a[6]);
  const float rdet = 1.0f/det;
  const float i00 =  (a[4]*a[8]-a[5]*a[7])*rdet;
  const float i01 = -(a[1]*a[8]-a[2]*a[7])*rdet;
  const float i02 =  (a[1]*a[5]-a[2]*a[4])*rdet;
  const float i10 = -(a[3]*a[8]-a[5]*a[6])*rdet;
  const float i11 =  (a[0]*a[8]-a[2]*a[6])*rdet;
  const float i12 = -(a[0]*a[5]-a[2]*a[3])*rdet;
  const float i20 =  (a[3]*a[7]-a[4]*a[6])*rdet;
  const float i21 = -(a[0]*a[7]-a[1]*a[6])*rdet;
  const float i22 =  (a[0]*a[4]-a[1]*a[3])*rdet;

  float acc[CDIM];
  #pragma unroll
  for(int c=0;c<CDIM;++c) acc[c]=0.0f;

  // ---- loop over this wave's 16 PSF vectors (v is wave-uniform -> s_loads) ----
  const int vbase = wvi * VPT;
  #pragma unroll 2
  for(int k=0;k<VPT;++k){
    const int v = vbase + k;
    const float sxv = psf[3*v+0];
    const float syv = psf[3*v+1];
    const float szv = psf[3*v+2];

    // vi_hat = A^{-1} @ psf[v]
    const float hx = fmaf(i00,sxv, fmaf(i01,syv, i02*szv));
    const float hy = fmaf(i10,sxv, fmaf(i11,syv, i12*szv));
    const float hz = fmaf(i20,sxv, fmaf(i21,syv, i22*szv));

    const float r2  = fmaf(hx,hx, fmaf(hy,hy, hz*hz));
    const float rin = rsqrtf(r2 + 1e-12f);        // hw rsqrt (~1 ulp): fine vs 1.6e-2 tol
    // xyz -> yzx permute, then normalize
    const float px = hy*rin;
    const float py = hz*rin;
    const float pz = hx*rin;

    const float modv = r2 * rin * det;            // sqrt(r2)*det == r2*rsqrt(r2)*det

    // w[v] = dot(M_p[v,:], img) — M_p row is wave-uniform (SGPR broadcast)
    const float* Mrow = Mp + v*CDIM;
    float w0=0.f,w1=0.f,w2=0.f,w3=0.f;
    #pragma unroll
    for(int c=0;c<44;c+=4){
      w0 = fmaf(Mrow[c+0], img[c+0], w0);
      w1 = fmaf(Mrow[c+1], img[c+1], w1);
      w2 = fmaf(Mrow[c+2], img[c+2], w2);
      w3 = fmaf(Mrow[c+3], img[c+3], w3);
    }
    w0 = fmaf(Mrow[44], img[44], w0);
    const float wval = (w0+w1)+(w2+w3);
    const float wmod = modv * wval;

    // A_m, B_m recurrence (Chebyshev)
    float Aa[LMAXX+1], Bb[LMAXX+1];
    Aa[0]=1.0f; Bb[0]=0.0f;
    cunroll<LMAXX>([&](auto Mc){
      constexpr int M = decltype(Mc)::value + 1;
      Aa[M] = fmaf(px, Aa[M-1], -(py*Bb[M-1]));
      Bb[M] = fmaf(px, Bb[M-1],  (py*Aa[M-1]));
    });

    // per |m|: Q recurrence + fused accumulate into acc[]
    cunroll<LMAXX+1>([&](auto AMc){
      constexpr int AM = decltype(AMc)::value;
      const float fa = wmod * Aa[AM];
      const float fb = wmod * Bb[AM];
      float qp2 = SHT.qmm[AM];        // Q[AM][AM]
      float qp1 = SHT.qnx[AM]*pz;     // Q[AM+1][AM]

      if constexpr ((AM&1)==0){       // l = AM (even): emit
        constexpr float C = SHT.CP[AM][AM];
        const float t = qp2 * C;
        if constexpr (AM==0){
          acc[0] = fmaf(t, wmod, acc[0]);
        } else {
          acc[offL(AM)+2*AM] = fmaf(t, fa, acc[offL(AM)+2*AM]);
          acc[offL(AM)+0   ] = fmaf(t, fb, acc[offL(AM)+0   ]);
        }
      }
      if constexpr (AM<LMAXX && (((AM+1)&1)==0)){  // l = AM+1 even
        constexpr int L = AM+1;
        constexpr float C = SHT.CP[AM][L];
        const float t = qp1 * C;
        acc[offL(L)+L+AM] = fmaf(t, fa, acc[offL(L)+L+AM]);
        acc[offL(L)+L-AM] = fmaf(t, fb, acc[offL(L)+L-AM]);
      }

      constexpr int CNT = (LMAXX-AM-1) > 0 ? (LMAXX-AM-1) : 0;  // l = AM+2..8
      cunroll<CNT>([&](auto Lc){
        constexpr int L = AM + 2 + decltype(Lc)::value;
        constexpr float C1 = SHT.c1[AM][L];
        constexpr float C2 = SHT.c2[AM][L];
        const float q = fmaf(C1*pz, qp1, -(C2*qp2));
        qp2 = qp1; qp1 = q;
        if constexpr ((L&1)==0){
          constexpr float C = SHT.CP[AM][L];
          const float t = q * C;
          if constexpr (AM==0){
            acc[offL(L)+L] = fmaf(t, wmod, acc[offL(L)+L]);
          } else {
            acc[offL(L)+L+AM] = fmaf(t, fa, acc[offL(L)+L+AM]);
            acc[offL(L)+L-AM] = fmaf(t, fb, acc[offL(L)+L-AM]);
          }
        }
      });
    });
  }

  // ---- cross-wave reduction over the 4 vector-splits ----
  #pragma unroll
  for(int c=0;c<CDIM;++c) red[wvi][lane][c] = acc[c];
  __syncthreads();

  const int total = VOXPB * CDIM;
  for(int i = tid; i < total; i += 256){
    const int vx = i / CDIM;
    if (voxBase + vx < Nvox){
      const int c = i - vx*CDIM;
      const float s = red[0][vx][c] + red[1][vx][c]
                    + red[2][vx][c] + red[3][vx][c];
      out[(long long)voxBase*CDIM + i] = s;
    }
  }
}

// ---------------- launch ----------------
extern "C" void kernel_launch(void* const* d_in, const int* in_sizes, int n_in,
                              void* d_out, int out_size, void* d_ws, size_t ws_size,
                              hipStream_t stream)
{
  const float* image  = (const float*)d_in[0];
  const float* affine = (const float*)d_in[1];
  const float* psf    = (const float*)d_in[2];
  const float* Mp     = (const float*)d_in[3];
  float* out = (float*)d_out;

  const int Nvox = in_sizes[0] / CDIM;
  const int blocks = (Nvox + VOXPB - 1) / VOXPB;

  hipLaunchKernelGGL(fodf_reorient_kernel, dim3(blocks), dim3(256), 0, stream,
                     image, affine, psf, Mp, out, Nvox);
}

// Round 7
// 79.850 us; speedup vs baseline: 1.7620x; 1.0016x over previous
//
#include <hip/hip_runtime.h>
#include <type_traits>
#include <utility>

#define CDIM   45
#define LMAXX  8
#define WAVES_PB 4
#define VOXPB  64
#define VDIM   64
#define VPT    (VDIM / WAVES_PB)

// ---------------- compile-time SH constant tables ----------------
// Normalization CP[m][l] is folded INTO the Q-recurrence (p_l = Q_l * CP[m][l])
// so emits are single FMAs; wmod is folded into the A/B recurrence seed.
constexpr double PI_D = 3.14159265358979323846;

constexpr double dfactd(int n){ double o=1.0; for(int k=n;k>1;k-=2) o*=k; return o; }
constexpr double factd (int n){ double o=1.0; for(int k=2;k<=n;++k) o*=k; return o; }
constexpr double csqrtd(double x){
  if(x<=0.0) return 0.0;
  double g = x>1.0 ? x : 1.0;
  for(int i=0;i<200;++i) g = 0.5*(g + x/g);
  return g;
}

// full combined constant for ALL l in [m,8]: m==0 ? K : sgn*sqrt2*K
constexpr double CPf(int m, int l){
  double K = csqrtd((2.0*l+1.0)/(4.0*PI_D)*factd(l-m)/factd(l+m));
  if (m==0) return K;
  return ((m&1)?-1.0:1.0)*csqrtd(2.0)*K;
}

struct SHTab {
  float c1[LMAXX+1][LMAXX+1];  // (2l-1)/(l-m) * CPf(l)/CPf(l-1)
  float c2[LMAXX+1][LMAXX+1];  // (l+m-1)/(l-m) * CPf(l)/CPf(l-2)
  float qmm[LMAXX+1];          // (-1)^m (2m-1)!! * CPf(m,m)      == p_m
  float qnx[LMAXX+1];          // (2m+1)*(-1)^m(2m-1)!! * CPf(m,m+1)  (p_{m+1}/pz)
};

constexpr SHTab makeTab(){
  SHTab t{};
  for(int m=0;m<=LMAXX;++m){
    double q = ((m&1)?-1.0:1.0)*dfactd(2*m-1);
    t.qmm[m]=(float)(q*CPf(m,m));
    t.qnx[m]=(m<LMAXX)?(float)((2.0*m+1.0)*q*CPf(m,m+1)):0.0f;
    for(int l=m+2;l<=LMAXX;++l){
      t.c1[m][l]=(float)((2.0*l-1.0)/(double)(l-m)*CPf(m,l)/CPf(m,l-1));
      t.c2[m][l]=(float)((double)(l+m-1)/(double)(l-m)*CPf(m,l)/CPf(m,l-2));
    }
  }
  return t;
}
constexpr SHTab SHT = makeTab();

// block offsets for even l: l=0,2,4,6,8 -> 0,1,6,15,28 ; idx(l,m)=offL(l)+l+m
constexpr int offL(int l){ return l==0?0 : (l==2?1 : (l==4?6 : (l==6?15 : 28))); }

// compile-time unroller (indices are constants -> acc[] stays in registers)
template<int N, typename F>
__device__ __forceinline__ void cunroll(F&& f){
  if constexpr (N > 0){
    cunroll<N-1>(f);
    f(std::integral_constant<int, N-1>{});
  }
}

// ---------------- kernel ----------------
__global__ __launch_bounds__(256, 2)
void fodf_reorient_kernel(const float* __restrict__ image,
                          const float* __restrict__ affine,
                          const float* __restrict__ psf,
                          const float* __restrict__ Mp,
                          float* __restrict__ out,
                          int Nvox)
{
  __shared__ float red[WAVES_PB][VOXPB][CDIM+3];   // pad 45->48 floats

  const int tid  = threadIdx.x;
  const int lane = tid & 63;
  const int wvi  = __builtin_amdgcn_readfirstlane(tid >> 6); // wave id 0..3 (uniform)
  const int voxBase = blockIdx.x * VOXPB;
  const int vox  = voxBase + lane;
  const bool valid = vox < Nvox;

  // ---- per-voxel loads (one lane = one voxel) ----
  float img[CDIM];
  if (valid){
    const float* ip = image + (long long)vox * CDIM;
    #pragma unroll
    for(int c=0;c<CDIM;++c) img[c] = ip[c];
  } else {
    #pragma unroll
    for(int c=0;c<CDIM;++c) img[c] = 0.0f;
  }

  float a[9];
  if (valid){
    const float* ap = affine + (long long)vox * 9;
    #pragma unroll
    for(int i=0;i<9;++i) a[i] = ap[i];
  } else {
    #pragma unroll
    for(int i=0;i<9;++i) a[i] = (i%4==0) ? 1.0f : 0.0f;   // identity
  }

  // ---- 3x3 inverse via adjugate ----
  const float det = a[0]*(a[4]*a[8]-a[5]*a[7])
                  - a[1]*(a[3]*a[8]-a[5]*a[6])
                  + a[2]*(a[3]*a[7]-a[4]*a[6]);
  const float rdet = 1.0f/det;
  const float i00 =  (a[4]*a[8]-a[5]*a[7])*rdet;
  const float i01 = -(a[1]*a[8]-a[2]*a[7])*rdet;
  const float i02 =  (a[1]*a[5]-a[2]*a[4])*rdet;
  const float i10 = -(a[3]*a[8]-a[5]*a[6])*rdet;
  const float i11 =  (a[0]*a[8]-a[2]*a[6])*rdet;
  const float i12 = -(a[0]*a[5]-a[2]*a[3])*rdet;
  const float i20 =  (a[3]*a[7]-a[4]*a[6])*rdet;
  const float i21 = -(a[0]*a[7]-a[1]*a[6])*rdet;
  const float i22 =  (a[0]*a[4]-a[1]*a[3])*rdet;

  float acc[CDIM];
  #pragma unroll
  for(int c=0;c<CDIM;++c) acc[c]=0.0f;

  // ---- loop over this wave's 16 PSF vectors (v is wave-uniform -> s_loads) ----
  const int vbase = wvi * VPT;
  #pragma unroll 4
  for(int k=0;k<VPT;++k){
    const int v = vbase + k;
    const float sxv = psf[3*v+0];
    const float syv = psf[3*v+1];
    const float szv = psf[3*v+2];

    // vi_hat = A^{-1} @ psf[v]
    const float hx = fmaf(i00,sxv, fmaf(i01,syv, i02*szv));
    const float hy = fmaf(i10,sxv, fmaf(i11,syv, i12*szv));
    const float hz = fmaf(i20,sxv, fmaf(i21,syv, i22*szv));

    const float r2  = fmaf(hx,hx, fmaf(hy,hy, hz*hz));
    const float rin = rsqrtf(r2 + 1e-12f);        // hw rsqrt (~1 ulp): fine vs 1.6e-2 tol
    // xyz -> yzx permute, then normalize
    const float px = hy*rin;
    const float py = hz*rin;
    const float pz = hx*rin;

    const float modv = r2 * rin * det;            // sqrt(r2)*det == r2*rsqrt(r2)*det

    // w[v] = dot(M_p[v,:], img) — M_p row is wave-uniform (SGPR broadcast)
    const float* Mrow = Mp + v*CDIM;
    float w0=0.f,w1=0.f,w2=0.f,w3=0.f;
    #pragma unroll
    for(int c=0;c<44;c+=4){
      w0 = fmaf(Mrow[c+0], img[c+0], w0);
      w1 = fmaf(Mrow[c+1], img[c+1], w1);
      w2 = fmaf(Mrow[c+2], img[c+2], w2);
      w3 = fmaf(Mrow[c+3], img[c+3], w3);
    }
    w0 = fmaf(Mrow[44], img[44], w0);
    const float wval = (w0+w1)+(w2+w3);
    const float wmod = modv * wval;

    // A_m, B_m recurrence (Chebyshev), SEEDED with wmod:
    // A'_m = wmod*A_m, B'_m = wmod*B_m (linear recurrence) -> fa/fb muls free
    float Aa[LMAXX+1], Bb[LMAXX+1];
    Aa[0]=wmod; Bb[0]=0.0f;
    cunroll<LMAXX>([&](auto Mc){
      constexpr int M = decltype(Mc)::value + 1;
      Aa[M] = fmaf(px, Aa[M-1], -(py*Bb[M-1]));
      Bb[M] = fmaf(px, Bb[M-1],  (py*Aa[M-1]));
    });

    // per |m|: CP-rescaled Q recurrence (p_l = Q_l*CP[m][l]) + fused accumulate
    cunroll<LMAXX+1>([&](auto AMc){
      constexpr int AM = decltype(AMc)::value;
      const float fa = Aa[AM];        // already wmod-scaled
      const float fb = Bb[AM];
      float qp2 = SHT.qmm[AM];        // p_AM
      float qp1 = SHT.qnx[AM]*pz;     // p_{AM+1} (0 for AM==8, dead)

      if constexpr ((AM&1)==0){       // l = AM (even): emit
        if constexpr (AM==0){
          acc[0] = fmaf(qp2, fa, acc[0]);
        } else {
          acc[offL(AM)+2*AM] = fmaf(qp2, fa, acc[offL(AM)+2*AM]);
          acc[offL(AM)+0   ] = fmaf(qp2, fb, acc[offL(AM)+0   ]);
        }
      }
      if constexpr (AM<LMAXX && (((AM+1)&1)==0)){  // l = AM+1 even
        constexpr int L = AM+1;
        acc[offL(L)+L+AM] = fmaf(qp1, fa, acc[offL(L)+L+AM]);
        acc[offL(L)+L-AM] = fmaf(qp1, fb, acc[offL(L)+L-AM]);
      }

      constexpr int CNT = (LMAXX-AM-1) > 0 ? (LMAXX-AM-1) : 0;  // l = AM+2..8
      cunroll<CNT>([&](auto Lc){
        constexpr int L = AM + 2 + decltype(Lc)::value;
        constexpr float C1 = SHT.c1[AM][L];
        constexpr float C2 = SHT.c2[AM][L];
        const float q = fmaf(C1*pz, qp1, -(C2*qp2));
        qp2 = qp1; qp1 = q;
        if constexpr ((L&1)==0){
          if constexpr (AM==0){
            acc[offL(L)+L] = fmaf(q, fa, acc[offL(L)+L]);
          } else {
            acc[offL(L)+L+AM] = fmaf(q, fa, acc[offL(L)+L+AM]);
            acc[offL(L)+L-AM] = fmaf(q, fb, acc[offL(L)+L-AM]);
          }
        }
      });
    });
  }

  // ---- cross-wave reduction over the 4 vector-splits ----
  #pragma unroll
  for(int c=0;c<CDIM;++c) red[wvi][lane][c] = acc[c];
  __syncthreads();

  const int total = VOXPB * CDIM;
  for(int i = tid; i < total; i += 256){
    const int vx = i / CDIM;
    if (voxBase + vx < Nvox){
      const int c = i - vx*CDIM;
      const float s = red[0][vx][c] + red[1][vx][c]
                    + red[2][vx][c] + red[3][vx][c];
      out[(long long)voxBase*CDIM + i] = s;
    }
  }
}

// ---------------- launch ----------------
extern "C" void kernel_launch(void* const* d_in, const int* in_sizes, int n_in,
                              void* d_out, int out_size, void* d_ws, size_t ws_size,
                              hipStream_t stream)
{
  const float* image  = (const float*)d_in[0];
  const float* affine = (const float*)d_in[1];
  const float* psf    = (const float*)d_in[2];
  const float* Mp     = (const float*)d_in[3];
  float* out = (float*)d_out;

  const int Nvox = in_sizes[0] / CDIM;
  const int blocks = (Nvox + VOXPB - 1) / VOXPB;

  hipLaunchKernelGGL(fodf_reorient_kernel, dim3(blocks), dim3(256), 0, stream,
                     image, affine, psf, Mp, out, Nvox);
}

// Round 8
// 79.485 us; speedup vs baseline: 1.7701x; 1.0046x over previous
//
#include <hip/hip_runtime.h>
#include <type_traits>
#include <utility>

#define CDIM   45
#define LMAXX  8
#define WAVES_PB 4
#define VOXPB  64
#define VDIM   64
#define VPT    (VDIM / WAVES_PB)

// ---------------- compile-time SH constant tables ----------------
// Normalization CP[m][l] is folded INTO the Q-recurrence (p_l = Q_l * CP[m][l])
// so emits are single FMAs; wmod is folded into the A/B recurrence seed.
constexpr double PI_D = 3.14159265358979323846;

constexpr double dfactd(int n){ double o=1.0; for(int k=n;k>1;k-=2) o*=k; return o; }
constexpr double factd (int n){ double o=1.0; for(int k=2;k<=n;++k) o*=k; return o; }
constexpr double csqrtd(double x){
  if(x<=0.0) return 0.0;
  double g = x>1.0 ? x : 1.0;
  for(int i=0;i<200;++i) g = 0.5*(g + x/g);
  return g;
}

// full combined constant for ALL l in [m,8]: m==0 ? K : sgn*sqrt2*K
constexpr double CPf(int m, int l){
  double K = csqrtd((2.0*l+1.0)/(4.0*PI_D)*factd(l-m)/factd(l+m));
  if (m==0) return K;
  return ((m&1)?-1.0:1.0)*csqrtd(2.0)*K;
}

struct SHTab {
  float c1[LMAXX+1][LMAXX+1];  // (2l-1)/(l-m) * CPf(l)/CPf(l-1)
  float c2[LMAXX+1][LMAXX+1];  // (l+m-1)/(l-m) * CPf(l)/CPf(l-2)
  float qmm[LMAXX+1];          // (-1)^m (2m-1)!! * CPf(m,m)      == p_m
  float qnx[LMAXX+1];          // (2m+1)*(-1)^m(2m-1)!! * CPf(m,m+1)  (p_{m+1}/pz)
};

constexpr SHTab makeTab(){
  SHTab t{};
  for(int m=0;m<=LMAXX;++m){
    double q = ((m&1)?-1.0:1.0)*dfactd(2*m-1);
    t.qmm[m]=(float)(q*CPf(m,m));
    t.qnx[m]=(m<LMAXX)?(float)((2.0*m+1.0)*q*CPf(m,m+1)):0.0f;
    for(int l=m+2;l<=LMAXX;++l){
      t.c1[m][l]=(float)((2.0*l-1.0)/(double)(l-m)*CPf(m,l)/CPf(m,l-1));
      t.c2[m][l]=(float)((double)(l+m-1)/(double)(l-m)*CPf(m,l)/CPf(m,l-2));
    }
  }
  return t;
}
constexpr SHTab SHT = makeTab();

// block offsets for even l: l=0,2,4,6,8 -> 0,1,6,15,28 ; idx(l,m)=offL(l)+l+m
constexpr int offL(int l){ return l==0?0 : (l==2?1 : (l==4?6 : (l==6?15 : 28))); }

// compile-time unroller (indices are constants -> acc[] stays in registers)
template<int N, typename F>
__device__ __forceinline__ void cunroll(F&& f){
  if constexpr (N > 0){
    cunroll<N-1>(f);
    f(std::integral_constant<int, N-1>{});
  }
}

// ---------------- kernel ----------------
// launch_bounds 2nd arg = min BLOCKS/CU (CUDA semantics, proven by round-3's
// (512,4)->VGPR64). (256,3): 3 blocks/CU = 12 waves/CU = 3 waves/SIMD,
// VGPR cap ~168, LDS 3*48KiB = 144 <= 160 ✓.
__global__ __launch_bounds__(256, 3)
void fodf_reorient_kernel(const float* __restrict__ image,
                          const float* __restrict__ affine,
                          const float* __restrict__ psf,
                          const float* __restrict__ Mp,
                          float* __restrict__ out,
                          int Nvox)
{
  __shared__ float red[WAVES_PB][VOXPB][CDIM+3];   // pad 45->48 floats

  const int tid  = threadIdx.x;
  const int lane = tid & 63;
  const int wvi  = __builtin_amdgcn_readfirstlane(tid >> 6); // wave id 0..3 (uniform)
  const int voxBase = blockIdx.x * VOXPB;
  const int vox  = voxBase + lane;
  const bool valid = vox < Nvox;

  // ---- per-voxel loads (one lane = one voxel) ----
  float img[CDIM];
  if (valid){
    const float* ip = image + (long long)vox * CDIM;
    #pragma unroll
    for(int c=0;c<CDIM;++c) img[c] = ip[c];
  } else {
    #pragma unroll
    for(int c=0;c<CDIM;++c) img[c] = 0.0f;
  }

  float a[9];
  if (valid){
    const float* ap = affine + (long long)vox * 9;
    #pragma unroll
    for(int i=0;i<9;++i) a[i] = ap[i];
  } else {
    #pragma unroll
    for(int i=0;i<9;++i) a[i] = (i%4==0) ? 1.0f : 0.0f;   // identity
  }

  // ---- 3x3 inverse via adjugate ----
  const float det = a[0]*(a[4]*a[8]-a[5]*a[7])
                  - a[1]*(a[3]*a[8]-a[5]*a[6])
                  + a[2]*(a[3]*a[7]-a[4]*a[6]);
  const float rdet = 1.0f/det;
  const float i00 =  (a[4]*a[8]-a[5]*a[7])*rdet;
  const float i01 = -(a[1]*a[8]-a[2]*a[7])*rdet;
  const float i02 =  (a[1]*a[5]-a[2]*a[4])*rdet;
  const float i10 = -(a[3]*a[8]-a[5]*a[6])*rdet;
  const float i11 =  (a[0]*a[8]-a[2]*a[6])*rdet;
  const float i12 = -(a[0]*a[5]-a[2]*a[3])*rdet;
  const float i20 =  (a[3]*a[7]-a[4]*a[6])*rdet;
  const float i21 = -(a[0]*a[7]-a[1]*a[6])*rdet;
  const float i22 =  (a[0]*a[4]-a[1]*a[3])*rdet;

  float acc[CDIM];
  #pragma unroll
  for(int c=0;c<CDIM;++c) acc[c]=0.0f;

  // ---- loop over this wave's 16 PSF vectors (v is wave-uniform -> s_loads) ----
  const int vbase = wvi * VPT;
  #pragma unroll 4
  for(int k=0;k<VPT;++k){
    const int v = vbase + k;
    const float sxv = psf[3*v+0];
    const float syv = psf[3*v+1];
    const float szv = psf[3*v+2];

    // vi_hat = A^{-1} @ psf[v]
    const float hx = fmaf(i00,sxv, fmaf(i01,syv, i02*szv));
    const float hy = fmaf(i10,sxv, fmaf(i11,syv, i12*szv));
    const float hz = fmaf(i20,sxv, fmaf(i21,syv, i22*szv));

    const float r2  = fmaf(hx,hx, fmaf(hy,hy, hz*hz));
    const float rin = rsqrtf(r2 + 1e-12f);        // hw rsqrt (~1 ulp): fine vs 1.6e-2 tol
    // xyz -> yzx permute, then normalize
    const float px = hy*rin;
    const float py = hz*rin;
    const float pz = hx*rin;

    const float modv = r2 * rin * det;            // sqrt(r2)*det == r2*rsqrt(r2)*det

    // w[v] = dot(M_p[v,:], img) — M_p row is wave-uniform (SGPR broadcast)
    const float* Mrow = Mp + v*CDIM;
    float w0=0.f,w1=0.f,w2=0.f,w3=0.f;
    #pragma unroll
    for(int c=0;c<44;c+=4){
      w0 = fmaf(Mrow[c+0], img[c+0], w0);
      w1 = fmaf(Mrow[c+1], img[c+1], w1);
      w2 = fmaf(Mrow[c+2], img[c+2], w2);
      w3 = fmaf(Mrow[c+3], img[c+3], w3);
    }
    w0 = fmaf(Mrow[44], img[44], w0);
    const float wval = (w0+w1)+(w2+w3);
    const float wmod = modv * wval;

    // A_m, B_m recurrence (Chebyshev), SEEDED with wmod:
    // A'_m = wmod*A_m, B'_m = wmod*B_m (linear recurrence) -> fa/fb muls free
    float Aa[LMAXX+1], Bb[LMAXX+1];
    Aa[0]=wmod; Bb[0]=0.0f;
    cunroll<LMAXX>([&](auto Mc){
      constexpr int M = decltype(Mc)::value + 1;
      Aa[M] = fmaf(px, Aa[M-1], -(py*Bb[M-1]));
      Bb[M] = fmaf(px, Bb[M-1],  (py*Aa[M-1]));
    });

    // per |m|: CP-rescaled Q recurrence (p_l = Q_l*CP[m][l]) + fused accumulate
    cunroll<LMAXX+1>([&](auto AMc){
      constexpr int AM = decltype(AMc)::value;
      const float fa = Aa[AM];        // already wmod-scaled
      const float fb = Bb[AM];
      float qp2 = SHT.qmm[AM];        // p_AM
      float qp1 = SHT.qnx[AM]*pz;     // p_{AM+1} (0 for AM==8, dead)

      if constexpr ((AM&1)==0){       // l = AM (even): emit
        if constexpr (AM==0){
          acc[0] = fmaf(qp2, fa, acc[0]);
        } else {
          acc[offL(AM)+2*AM] = fmaf(qp2, fa, acc[offL(AM)+2*AM]);
          acc[offL(AM)+0   ] = fmaf(qp2, fb, acc[offL(AM)+0   ]);
        }
      }
      if constexpr (AM<LMAXX && (((AM+1)&1)==0)){  // l = AM+1 even
        constexpr int L = AM+1;
        acc[offL(L)+L+AM] = fmaf(qp1, fa, acc[offL(L)+L+AM]);
        acc[offL(L)+L-AM] = fmaf(qp1, fb, acc[offL(L)+L-AM]);
      }

      constexpr int CNT = (LMAXX-AM-1) > 0 ? (LMAXX-AM-1) : 0;  // l = AM+2..8
      cunroll<CNT>([&](auto Lc){
        constexpr int L = AM + 2 + decltype(Lc)::value;
        constexpr float C1 = SHT.c1[AM][L];
        constexpr float C2 = SHT.c2[AM][L];
        const float q = fmaf(C1*pz, qp1, -(C2*qp2));
        qp2 = qp1; qp1 = q;
        if constexpr ((L&1)==0){
          if constexpr (AM==0){
            acc[offL(L)+L] = fmaf(q, fa, acc[offL(L)+L]);
          } else {
            acc[offL(L)+L+AM] = fmaf(q, fa, acc[offL(L)+L+AM]);
            acc[offL(L)+L-AM] = fmaf(q, fb, acc[offL(L)+L-AM]);
          }
        }
      });
    });
  }

  // ---- cross-wave reduction over the 4 vector-splits ----
  #pragma unroll
  for(int c=0;c<CDIM;++c) red[wvi][lane][c] = acc[c];
  __syncthreads();

  const int total = VOXPB * CDIM;
  for(int i = tid; i < total; i += 256){
    const int vx = i / CDIM;
    if (voxBase + vx < Nvox){
      const int c = i - vx*CDIM;
      const float s = red[0][vx][c] + red[1][vx][c]
                    + red[2][vx][c] + red[3][vx][c];
      out[(long long)voxBase*CDIM + i] = s;
    }
  }
}

// ---------------- launch ----------------
extern "C" void kernel_launch(void* const* d_in, const int* in_sizes, int n_in,
                              void* d_out, int out_size, void* d_ws, size_t ws_size,
                              hipStream_t stream)
{
  const float* image  = (const float*)d_in[0];
  const float* affine = (const float*)d_in[1];
  const float* psf    = (const float*)d_in[2];
  const float* Mp     = (const float*)d_in[3];
  float* out = (float*)d_out;

  const int Nvox = in_sizes[0] / CDIM;
  const int blocks = (Nvox + VOXPB - 1) / VOXPB;

  hipLaunchKernelGGL(fodf_reorient_kernel, dim3(blocks), dim3(256), 0, stream,
                     image, affine, psf, Mp, out, Nvox);
}